// Round 7
// baseline (95.951 us; speedup 1.0000x reference)
//
#include <hip/hip_runtime.h>
#include <hip/hip_bf16.h>

#define NROWS 8192
#define DCOLS 256
#define NTILES 2080   // 64*65/2 upper-triangle 128x128 tiles
constexpr float EPSV = 1e-6f;

typedef __attribute__((ext_vector_type(8))) short short8;
typedef __attribute__((ext_vector_type(4))) float f32x4;

__device__ __forceinline__ void async16(void* lds, const void* g) {
    __builtin_amdgcn_global_load_lds(
        (const __attribute__((address_space(1))) void*)g,
        (__attribute__((address_space(3))) void*)lds, 16, 0, 0);
}

// ---------------- K12: row norms + per-block colsum partials (no atomics) ----------------
__global__ void k12_fused(const float* __restrict__ in, float* __restrict__ inv,
                          float* __restrict__ part) {
    int t = threadIdx.x, lane = t & 63, wave = t >> 6;
    int r0 = blockIdx.x * 32;
    __shared__ float cs[4][256];
    float4 acc4 = {0.f, 0.f, 0.f, 0.f};
    #pragma unroll
    for (int rr = 0; rr < 8; ++rr) {
        int row = r0 + wave * 8 + rr;
        float4 v = *reinterpret_cast<const float4*>(&in[row * DCOLS + lane * 4]);
        float s = v.x * v.x + v.y * v.y + v.z * v.z + v.w * v.w;
        #pragma unroll
        for (int o = 1; o < 64; o <<= 1) s += __shfl_xor(s, o);
        float iv = 1.0f / (sqrtf(s) + EPSV);
        if (lane == 0) inv[row] = iv;
        acc4.x += v.x * iv; acc4.y += v.y * iv; acc4.z += v.z * iv; acc4.w += v.w * iv;
    }
    *reinterpret_cast<float4*>(&cs[wave][lane * 4]) = acc4;
    __syncthreads();
    part[blockIdx.x * 256 + t] = cs[0][t] + cs[1][t] + cs[2][t] + cs[3][t];
}

// ---------------- K3: reduce partials -> colmean; center; bf16 c; sq_norms ----------------
__global__ void k3_center(const float* __restrict__ in, const float* __restrict__ inv,
                          const float* __restrict__ part,
                          __hip_bfloat16* __restrict__ cbf, float* __restrict__ sqn) {
    int t = threadIdx.x, lane = t & 63, wave = t >> 6;
    int r0 = blockIdx.x * 32;
    __shared__ float cm[256];
    float m = 0.f;
    #pragma unroll 8
    for (int b = 0; b < 256; ++b) m += part[b * 256 + t];
    cm[t] = m * (1.0f / NROWS);
    __syncthreads();
    float4 m4 = *reinterpret_cast<const float4*>(&cm[lane * 4]);
    #pragma unroll
    for (int rr = 0; rr < 8; ++rr) {
        int row = r0 + wave * 8 + rr;
        float iv = inv[row];
        float4 v = *reinterpret_cast<const float4*>(&in[row * DCOLS + lane * 4]);
        float4 cv = {v.x * iv - m4.x, v.y * iv - m4.y, v.z * iv - m4.z, v.w * iv - m4.w};
        __hip_bfloat16 hb[4] = {__float2bfloat16(cv.x), __float2bfloat16(cv.y),
                                __float2bfloat16(cv.z), __float2bfloat16(cv.w)};
        *reinterpret_cast<ushort4*>(&cbf[row * DCOLS + lane * 4]) = *reinterpret_cast<ushort4*>(hb);
        float s = cv.x * cv.x + cv.y * cv.y + cv.z * cv.z + cv.w * cv.w;
        #pragma unroll
        for (int o = 1; o < 64; o <<= 1) s += __shfl_xor(s, o);
        if (lane == 0) sqn[row] = s;
    }
}

// ---------------- K4: 128x128 tile, 8 waves (64x32 each), SINGLE-buffer BK=64 ----------------
// 32KB LDS -> 4 blocks/CU -> 32 waves/CU. Two barriers per K-step; cross-block TLP
// hides the drains. Swizzle on GLOBAL source (LDS linear), XOR byte^=((row&7)<<4).
__global__ __launch_bounds__(512, 8) void k4_dist(const __hip_bfloat16* __restrict__ cbf,
                                                  const float* __restrict__ sqn,
                                                  float* __restrict__ partial) {
    __shared__ ushort As[128 * 64];   // 16KB
    __shared__ ushort Bs[128 * 64];   // 16KB
    __shared__ float sqA[128], sqB[128];
    __shared__ float red8[8];

    int bid = blockIdx.x;
    int idx = (bid & 7) * (NTILES / 8) + (bid >> 3);   // XCD swizzle, 2080%8==0
    int q = (int)((sqrtf(8.0f * (float)idx + 1.0f) - 1.0f) * 0.5f);
    while ((q + 1) * (q + 2) / 2 <= idx) ++q;
    while (q * (q + 1) / 2 > idx) --q;
    int p = idx - q * (q + 1) / 2;

    int brow = p * 128, bcol = q * 128;
    int t = threadIdx.x, lane = t & 63, wave = t >> 6;
    int wr = wave >> 2, wc = wave & 3;

    // lane l covers LDS row r0+(l>>3), 16B chunk ((l&7)^(l>>3)) of the 128B row
    int laneOff = ((lane >> 3) * 512) + ((((lane & 7) ^ (lane >> 3)) & 7) << 4);
    const char* Ab = (const char*)cbf + (size_t)brow * 512 + laneOff;
    const char* Bb = (const char*)cbf + (size_t)bcol * 512 + laneOff;
    int ra = 16 * wave;        // this wave's staging rows: ra..ra+7, ra+8..ra+15

    // stage sqn slices once
    if (t < 128) sqA[t] = sqn[brow + t];
    else if (t < 256) sqB[t - 128] = sqn[bcol + t - 128];

    f32x4 acc[4][2] = {};

    #pragma unroll
    for (int s = 0; s < 4; ++s) {
        if (s) __syncthreads();          // all reads of previous slice done
        int kb = s * 128;
        async16(&As[ra * 64], Ab + ra * 512 + kb);
        async16(&As[(ra + 8) * 64], Ab + (ra + 8) * 512 + kb);
        async16(&Bs[ra * 64], Bb + ra * 512 + kb);
        async16(&Bs[(ra + 8) * 64], Bb + (ra + 8) * 512 + kb);
        __syncthreads();                 // vmcnt(0) drain: slice staged
        #pragma unroll
        for (int kk = 0; kk < 2; ++kk) {
            short8 af[4], bfr[2];
            int bc = kk * 64 + ((lane >> 4) << 4);
            #pragma unroll
            for (int m = 0; m < 4; ++m) {
                int row = wr * 64 + m * 16 + (lane & 15);
                int off = (row * 128 + bc) ^ ((row & 7) << 4);
                af[m] = *reinterpret_cast<const short8*>(reinterpret_cast<const char*>(As) + off);
            }
            #pragma unroll
            for (int n = 0; n < 2; ++n) {
                int row = wc * 32 + n * 16 + (lane & 15);
                int off = (row * 128 + bc) ^ ((row & 7) << 4);
                bfr[n] = *reinterpret_cast<const short8*>(reinterpret_cast<const char*>(Bs) + off);
            }
            #pragma unroll
            for (int m = 0; m < 4; ++m)
                #pragma unroll
                for (int n = 0; n < 2; ++n)
                    acc[m][n] = __builtin_amdgcn_mfma_f32_16x16x32_bf16(af[m], bfr[n], acc[m][n], 0, 0, 0);
        }
    }

    // epilogue: sq_dist = sqn_i + sqn_j - 2*gram; accumulate sqrt
    float local = 0.0f;
    int r4 = (lane >> 4) * 4;
    int cn = lane & 15;
    #pragma unroll
    for (int n = 0; n < 2; ++n) {
        float sj = sqB[wc * 32 + n * 16 + cn];
        #pragma unroll
        for (int m = 0; m < 4; ++m) {
            int i0 = wr * 64 + m * 16 + r4;
            #pragma unroll
            for (int r = 0; r < 4; ++r) {
                float sq = sqA[i0 + r] + sj - 2.0f * acc[m][n][r];
                local += (sq > 0.0f) ? sqrtf(sq) : 0.0f;
            }
        }
    }
    #pragma unroll
    for (int o = 1; o < 64; o <<= 1) local += __shfl_xor(local, o);
    if (lane == 0) red8[wave] = local;
    __syncthreads();
    if (t == 0) {
        float w = (p == q) ? 1.0f : 2.0f;
        float s8 = 0.f;
        #pragma unroll
        for (int i = 0; i < 8; ++i) s8 += red8[i];
        partial[idx] = w * s8;
    }
}

// ---------------- K5: final scalar ----------------
__global__ void k5_final(const float* __restrict__ sqn, const float* __restrict__ partial,
                         float* __restrict__ out) {
    int t = threadIdx.x;
    int lane = t & 63, wave = t >> 6;
    float s = 0.0f;
    for (int r = t; r < NROWS; r += 1024) s += sqn[r];
    double ds = 0.0;
    for (int r = t; r < NTILES; r += 1024) ds += (double)partial[r];
    #pragma unroll
    for (int o = 1; o < 64; o <<= 1) { s += __shfl_xor(s, o); ds += __shfl_xor(ds, o); }
    __shared__ float redf[16];
    __shared__ double redd[16];
    if (lane == 0) { redf[wave] = s; redd[wave] = ds; }
    __syncthreads();
    if (t == 0) {
        float sumsq = 0.f; double sd = 0.0;
        #pragma unroll
        for (int i = 0; i < 16; ++i) { sumsq += redf[i]; sd += redd[i]; }
        double md = sd / ((double)NROWS * (double)NROWS);
        out[0] = (float)DCOLS / sumsq + (float)log(md);
    }
}

extern "C" void kernel_launch(void* const* d_in, const int* in_sizes, int n_in,
                              void* d_out, int out_size, void* d_ws, size_t ws_size,
                              hipStream_t stream) {
    const float* emb = (const float*)d_in[0];
    float* out = (float*)d_out;
    char* ws = (char*)d_ws;

    float*  inv     = (float*)ws;                    // 8192 f32
    float*  sqn     = (float*)(ws + 36864);          // 8192 f32
    float*  partial = (float*)(ws + 69632);          // 2080 f32
    float*  part    = (float*)(ws + 81920);          // 256*256 f32 = 256KB
    __hip_bfloat16* cbf = (__hip_bfloat16*)(ws + 81920 + 262144); // 4 MB

    k12_fused <<<NROWS / 32, 256, 0, stream>>>(emb, inv, part);
    k3_center <<<NROWS / 32, 256, 0, stream>>>(emb, inv, part, cbf, sqn);
    k4_dist   <<<NTILES, 512, 0, stream>>>(cbf, sqn, partial);
    k5_final  <<<1, 1024, 0, stream>>>(sqn, partial, out);
}

// Round 8
// 63.442 us; speedup vs baseline: 1.5124x; 1.5124x over previous
//
#include <hip/hip_runtime.h>
#include <hip/hip_bf16.h>

#define NROWS 8192
#define DCOLS 256
#define NTILES 2080   // 64*65/2 upper-triangle 128x128 tiles
constexpr float EPSV = 1e-6f;

typedef __attribute__((ext_vector_type(8))) short short8;
typedef __attribute__((ext_vector_type(4))) float f32x4;

__device__ __forceinline__ void async16(void* lds, const void* g) {
    __builtin_amdgcn_global_load_lds(
        (const __attribute__((address_space(1))) void*)g,
        (__attribute__((address_space(3))) void*)lds, 16, 0, 0);
}

// ---------------- K12: row norms + per-block colsum partials (no atomics) ----------------
__global__ void k12_fused(const float* __restrict__ in, float* __restrict__ inv,
                          float* __restrict__ part) {
    int t = threadIdx.x, lane = t & 63, wave = t >> 6;
    int r0 = blockIdx.x * 32;
    __shared__ float cs[4][256];
    float4 acc4 = {0.f, 0.f, 0.f, 0.f};
    #pragma unroll
    for (int rr = 0; rr < 8; ++rr) {
        int row = r0 + wave * 8 + rr;
        float4 v = *reinterpret_cast<const float4*>(&in[row * DCOLS + lane * 4]);
        float s = v.x * v.x + v.y * v.y + v.z * v.z + v.w * v.w;
        #pragma unroll
        for (int o = 1; o < 64; o <<= 1) s += __shfl_xor(s, o);
        float iv = 1.0f / (sqrtf(s) + EPSV);
        if (lane == 0) inv[row] = iv;
        acc4.x += v.x * iv; acc4.y += v.y * iv; acc4.z += v.z * iv; acc4.w += v.w * iv;
    }
    *reinterpret_cast<float4*>(&cs[wave][lane * 4]) = acc4;
    __syncthreads();
    part[blockIdx.x * 256 + t] = cs[0][t] + cs[1][t] + cs[2][t] + cs[3][t];
}

// ---------------- K3: reduce partials -> colmean; center; bf16 c; sq_norms ----------------
__global__ void k3_center(const float* __restrict__ in, const float* __restrict__ inv,
                          const float* __restrict__ part,
                          __hip_bfloat16* __restrict__ cbf, float* __restrict__ sqn) {
    int t = threadIdx.x, lane = t & 63, wave = t >> 6;
    int r0 = blockIdx.x * 32;
    __shared__ float cm[256];
    float m = 0.f;
    #pragma unroll 8
    for (int b = 0; b < 256; ++b) m += part[b * 256 + t];
    cm[t] = m * (1.0f / NROWS);
    __syncthreads();
    float4 m4 = *reinterpret_cast<const float4*>(&cm[lane * 4]);
    #pragma unroll
    for (int rr = 0; rr < 8; ++rr) {
        int row = r0 + wave * 8 + rr;
        float iv = inv[row];
        float4 v = *reinterpret_cast<const float4*>(&in[row * DCOLS + lane * 4]);
        float4 cv = {v.x * iv - m4.x, v.y * iv - m4.y, v.z * iv - m4.z, v.w * iv - m4.w};
        __hip_bfloat16 hb[4] = {__float2bfloat16(cv.x), __float2bfloat16(cv.y),
                                __float2bfloat16(cv.z), __float2bfloat16(cv.w)};
        *reinterpret_cast<ushort4*>(&cbf[row * DCOLS + lane * 4]) = *reinterpret_cast<ushort4*>(hb);
        float s = cv.x * cv.x + cv.y * cv.y + cv.z * cv.z + cv.w * cv.w;
        #pragma unroll
        for (int o = 1; o < 64; o <<= 1) s += __shfl_xor(s, o);
        if (lane == 0) sqn[row] = s;
    }
}

// ---------------- K4: 128x128 tile, 8 waves (64x32 each), SINGLE-buffer BK=64 ----------------
// 32KB LDS + ~52 VGPR -> 4 blocks/CU by wave slots. launch_bounds(512,4) -> VGPR cap 128
// (NO spills; (512,8) spilled 104MB to scratch in round 7).
__global__ __launch_bounds__(512, 4) void k4_dist(const __hip_bfloat16* __restrict__ cbf,
                                                  const float* __restrict__ sqn,
                                                  float* __restrict__ partial) {
    __shared__ ushort As[128 * 64];   // 16KB
    __shared__ ushort Bs[128 * 64];   // 16KB
    __shared__ float sqA[128], sqB[128];
    __shared__ float red8[8];

    int bid = blockIdx.x;
    int idx = (bid & 7) * (NTILES / 8) + (bid >> 3);   // XCD swizzle, 2080%8==0
    int q = (int)((sqrtf(8.0f * (float)idx + 1.0f) - 1.0f) * 0.5f);
    while ((q + 1) * (q + 2) / 2 <= idx) ++q;
    while (q * (q + 1) / 2 > idx) --q;
    int p = idx - q * (q + 1) / 2;

    int brow = p * 128, bcol = q * 128;
    int t = threadIdx.x, lane = t & 63, wave = t >> 6;
    int wr = wave >> 2, wc = wave & 3;

    // lane l covers LDS row r0+(l>>3), 16B chunk ((l&7)^(l>>3)) of the 128B row
    int laneOff = ((lane >> 3) * 512) + ((((lane & 7) ^ (lane >> 3)) & 7) << 4);
    const char* Ab = (const char*)cbf + (size_t)brow * 512 + laneOff;
    const char* Bb = (const char*)cbf + (size_t)bcol * 512 + laneOff;
    int ra = 16 * wave;        // this wave's staging rows: ra..ra+7, ra+8..ra+15

    // stage sqn slices once
    if (t < 128) sqA[t] = sqn[brow + t];
    else if (t < 256) sqB[t - 128] = sqn[bcol + t - 128];

    f32x4 acc[4][2] = {};

    #pragma unroll
    for (int s = 0; s < 4; ++s) {
        if (s) __syncthreads();          // all reads of previous slice done
        int kb = s * 128;
        async16(&As[ra * 64], Ab + ra * 512 + kb);
        async16(&As[(ra + 8) * 64], Ab + (ra + 8) * 512 + kb);
        async16(&Bs[ra * 64], Bb + ra * 512 + kb);
        async16(&Bs[(ra + 8) * 64], Bb + (ra + 8) * 512 + kb);
        __syncthreads();                 // vmcnt(0) drain: slice staged
        #pragma unroll
        for (int kk = 0; kk < 2; ++kk) {
            short8 af[4], bfr[2];
            int bc = kk * 64 + ((lane >> 4) << 4);
            #pragma unroll
            for (int m = 0; m < 4; ++m) {
                int row = wr * 64 + m * 16 + (lane & 15);
                int off = (row * 128 + bc) ^ ((row & 7) << 4);
                af[m] = *reinterpret_cast<const short8*>(reinterpret_cast<const char*>(As) + off);
            }
            #pragma unroll
            for (int n = 0; n < 2; ++n) {
                int row = wc * 32 + n * 16 + (lane & 15);
                int off = (row * 128 + bc) ^ ((row & 7) << 4);
                bfr[n] = *reinterpret_cast<const short8*>(reinterpret_cast<const char*>(Bs) + off);
            }
            #pragma unroll
            for (int m = 0; m < 4; ++m)
                #pragma unroll
                for (int n = 0; n < 2; ++n)
                    acc[m][n] = __builtin_amdgcn_mfma_f32_16x16x32_bf16(af[m], bfr[n], acc[m][n], 0, 0, 0);
        }
    }

    // epilogue: sq_dist = sqn_i + sqn_j - 2*gram; accumulate sqrt
    float local = 0.0f;
    int r4 = (lane >> 4) * 4;
    int cn = lane & 15;
    #pragma unroll
    for (int n = 0; n < 2; ++n) {
        float sj = sqB[wc * 32 + n * 16 + cn];
        #pragma unroll
        for (int m = 0; m < 4; ++m) {
            int i0 = wr * 64 + m * 16 + r4;
            #pragma unroll
            for (int r = 0; r < 4; ++r) {
                float sq = sqA[i0 + r] + sj - 2.0f * acc[m][n][r];
                local += (sq > 0.0f) ? sqrtf(sq) : 0.0f;
            }
        }
    }
    #pragma unroll
    for (int o = 1; o < 64; o <<= 1) local += __shfl_xor(local, o);
    if (lane == 0) red8[wave] = local;
    __syncthreads();
    if (t == 0) {
        float w = (p == q) ? 1.0f : 2.0f;
        float s8 = 0.f;
        #pragma unroll
        for (int i = 0; i < 8; ++i) s8 += red8[i];
        partial[idx] = w * s8;
    }
}

// ---------------- K5: final scalar ----------------
__global__ void k5_final(const float* __restrict__ sqn, const float* __restrict__ partial,
                         float* __restrict__ out) {
    int t = threadIdx.x;
    int lane = t & 63, wave = t >> 6;
    float s = 0.0f;
    for (int r = t; r < NROWS; r += 1024) s += sqn[r];
    double ds = 0.0;
    for (int r = t; r < NTILES; r += 1024) ds += (double)partial[r];
    #pragma unroll
    for (int o = 1; o < 64; o <<= 1) { s += __shfl_xor(s, o); ds += __shfl_xor(ds, o); }
    __shared__ float redf[16];
    __shared__ double redd[16];
    if (lane == 0) { redf[wave] = s; redd[wave] = ds; }
    __syncthreads();
    if (t == 0) {
        float sumsq = 0.f; double sd = 0.0;
        #pragma unroll
        for (int i = 0; i < 16; ++i) { sumsq += redf[i]; sd += redd[i]; }
        double md = sd / ((double)NROWS * (double)NROWS);
        out[0] = (float)DCOLS / sumsq + (float)log(md);
    }
}

extern "C" void kernel_launch(void* const* d_in, const int* in_sizes, int n_in,
                              void* d_out, int out_size, void* d_ws, size_t ws_size,
                              hipStream_t stream) {
    const float* emb = (const float*)d_in[0];
    float* out = (float*)d_out;
    char* ws = (char*)d_ws;

    float*  inv     = (float*)ws;                    // 8192 f32
    float*  sqn     = (float*)(ws + 36864);          // 8192 f32
    float*  partial = (float*)(ws + 69632);          // 2080 f32
    float*  part    = (float*)(ws + 81920);          // 256*256 f32 = 256KB
    __hip_bfloat16* cbf = (__hip_bfloat16*)(ws + 81920 + 262144); // 4 MB

    k12_fused <<<NROWS / 32, 256, 0, stream>>>(emb, inv, part);
    k3_center <<<NROWS / 32, 256, 0, stream>>>(emb, inv, part, cbf, sqn);
    k4_dist   <<<NTILES, 512, 0, stream>>>(cbf, sqn, partial);
    k5_final  <<<1, 1024, 0, stream>>>(sqn, partial, out);
}